// Round 3
// baseline (319.506 us; speedup 1.0000x reference)
//
#include <hip/hip_runtime.h>

typedef unsigned short u16;
typedef unsigned int u32;
typedef __attribute__((ext_vector_type(8))) short short8;   // 8 bf16 = 4 VGPR (MFMA A/B frag)
typedef __attribute__((ext_vector_type(4))) float f32x4;    // MFMA C/D frag
typedef __attribute__((ext_vector_type(2))) u32 u32x2;
typedef const __attribute__((address_space(1))) unsigned int g_u32;
typedef __attribute__((address_space(3))) unsigned int l_u32;

#define BATCH 16384
#define XCOLS 2048

__device__ __forceinline__ void gload16(const void* g, void* l) {
  // async global->LDS, 16B/lane; LDS dest = wave-uniform base + lane*16
  __builtin_amdgcn_global_load_lds((g_u32*)g, (l_u32*)l, 16, 0, 0);
}
__device__ __forceinline__ u16 f2bf(float f) {   // RNE f32->bf16
  u32 x = __builtin_bit_cast(u32, f);
  x += 0x7fffu + ((x >> 16) & 1u);
  return (u16)(x >> 16);
}
// XOR-swizzle on byte offsets with 128B lines: 16B-slot ^= line&7
__device__ __forceinline__ int swz(int P) { return P ^ (((P >> 7) & 7) << 4); }

__device__ __forceinline__ float fast_tanh(float x) {
  // tanh(x) = 1 - 2/(exp2(x*2log2e)+1); saturates correctly at +-inf
  float e = __builtin_amdgcn_exp2f(x * 2.885390081777927f);
  return __builtin_fmaf(-2.0f, __builtin_amdgcn_rcpf(e + 1.0f), 1.0f);
}

// PI/PJ pair tables packed 3 bits per entry (octal digits, p=20..0 left->right)
#define PIPK 0544333222211111000000ULL
#define PJPK 0665654654365432654321ULL

// ---------------- prep: ctx f32 -> bf16 into X[:,0:1792] ----------------
__global__ void prep_ctx(const float* __restrict__ ctx, u16* __restrict__ X) {
  const int total = BATCH * 224;                     // 1792/8 octets per row
  for (int u = blockIdx.x * blockDim.x + threadIdx.x; u < total;
       u += gridDim.x * blockDim.x) {
    int b = u / 224, c8 = u - b * 224;
    const float4* s = (const float4*)(ctx + (size_t)b * 1792 + c8 * 8);
    float4 v0 = s[0], v1 = s[1];
    short8 o;
    o[0] = (short)f2bf(v0.x); o[1] = (short)f2bf(v0.y);
    o[2] = (short)f2bf(v0.z); o[3] = (short)f2bf(v0.w);
    o[4] = (short)f2bf(v1.x); o[5] = (short)f2bf(v1.y);
    o[6] = (short)f2bf(v1.z); o[7] = (short)f2bf(v1.w);
    *(short8*)(X + (size_t)b * XCOLS + c8 * 8) = o;
  }
}

// --------- prep: WcT[n][k] (n<256: W_rel[k][n]; else W_rel[256+k][n-256]) ---------
__global__ void prep_wrel(const float* __restrict__ Wr, u16* __restrict__ WcT) {
  int idx = blockIdx.x * 256 + threadIdx.x;          // 512*256
  if (idx >= 512 * 256) return;
  int n = idx >> 8, k = idx & 255;
  float v = (n < 256) ? Wr[k * 256 + n] : Wr[(256 + k) * 256 + (n - 256)];
  WcT[idx] = f2bf(v);
}

// --------- prep: WfcT[n][k] = bf16(W_fc[k][n]), LDS-tiled transpose ---------
__global__ void prep_wfc(const float* __restrict__ W, u16* __restrict__ WT) {
  __shared__ float t[64][65];
  int k0 = blockIdx.x * 64;                          // 32 blocks (K=2048)
  int n0 = blockIdx.y * 64;                          // 16 blocks (N=1024)
  int tx = threadIdx.x & 63, ty = threadIdx.x >> 6;  // 256 thr
  #pragma unroll
  for (int i = 0; i < 64; i += 4)
    t[ty + i][tx] = W[(size_t)(k0 + ty + i) * 1024 + n0 + tx];
  __syncthreads();
  #pragma unroll
  for (int i = 0; i < 64; i += 4) {
    int n = ty + i;
    WT[(size_t)(n0 + n) * XCOLS + k0 + tx] = f2bf(t[tx][n]);
  }
}

// ---------------- fused GEMM-1 + tanh + shuffled pair-sum ----------------
// block: 8 batches (56 rows pad 64), N=512, K=256, BK=64, 512 thr (8 waves 1x8)
// MFMA operands swapped -> D transposed: h on reg axis (b128 f32 UV staging),
// epilogue: 2 rounds x 28 rows; tanh on 4-elem chunks, segmented LDS-atomic sums.
__global__ __launch_bounds__(512, 4) void gemm1_fused(u16* __restrict__ X, const u16* __restrict__ WcT,
                                                      const float* __restrict__ b_rel) {
  // 73728 B: GEMM A[0,8192) B[8192,73728) ; epilogue UV f32 [0,57344) relbuf [57344,65536)
  __shared__ __align__(16) u16 smem[36864];
  char* sb = (char*)smem;
  float* relbuf = (float*)(sb + 57344);
  const int tid = threadIdx.x;
  const int wid = tid >> 6, lane = tid & 63;
  const int b_base = blockIdx.x * 8;
  // bias frags: waves 0-3 hold U cols (h<256) -> add b_rel there; waves 4-7 add 0
  f32x4 bias[4] = {};
  if (wid < 4) {
    #pragma unroll
    for (int n = 0; n < 4; ++n)
      bias[n] = *(const f32x4*)(b_rel + wid * 64 + n * 16 + ((lane >> 4) << 2));
  }
  f32x4 acc[4][4] = {};
  for (int kt = 0; kt < 4; ++kt) {
    const int kb = kt * 64;
    { // A: 64x64 bf16 = 8KB (rows 128B), 1 gload16/thread
      int L = swz(tid * 16);
      int row = L >> 7, koff = (L & 127) >> 1;
      int r = row < 56 ? row : 55;                   // pad rows clamp
      int bl = r / 7, e = r - bl * 7;
      gload16(X + (size_t)(b_base + bl) * XCOLS + e * 256 + kb + koff, sb + wid * 1024);
    }
    #pragma unroll
    for (int i = 0; i < 8; ++i) {                    // B: 512x64 bf16 = 64KB
      int slot = i * 512 + tid;
      int L = swz(slot * 16);
      int rn = L >> 7, koff = (L & 127) >> 1;
      gload16(WcT + rn * 256 + kb + koff, sb + 8192 + (i * 512 + wid * 64) * 16);
    }
    __syncthreads();
    #pragma unroll
    for (int kk = 0; kk < 64; kk += 32) {
      short8 a[4], b[4];
      #pragma unroll
      for (int m = 0; m < 4; ++m) {
        int row = m * 16 + (lane & 15);
        int L = row * 128 + kk * 2 + ((lane >> 4) << 4);
        a[m] = *(const short8*)(sb + swz(L));
      }
      #pragma unroll
      for (int n = 0; n < 4; ++n) {
        int rn = wid * 64 + n * 16 + (lane & 15);
        int L = rn * 128 + kk * 2 + ((lane >> 4) << 4);
        b[n] = *(const short8*)(sb + 8192 + swz(L));
      }
      // swapped operands: D[h][batch] -> h on reg axis, batch on lane&15
      #pragma unroll
      for (int m = 0; m < 4; ++m)
        #pragma unroll
        for (int n = 0; n < 4; ++n)
          acc[m][n] = __builtin_amdgcn_mfma_f32_16x16x32_bf16(b[n], a[m], acc[m][n], 0, 0, 0);
    }
    __syncthreads();
  }
  // zero relbuf (2048 f32): one f32x4 per thread
  *(f32x4*)(sb + 57344 + tid * 16) = f32x4{0.f, 0.f, 0.f, 0.f};
  // ---- 2 rounds x 28 rows (4 batches each) ----
  for (int rd = 0; rd < 2; ++rd) {
    const int rbase = rd * 28;
    // stage UV f32 [28][512] rows 2048B, XOR-swizzled; bias baked into U half
    #pragma unroll
    for (int m = 0; m < 4; ++m) {
      int row = m * 16 + (lane & 15);
      int lr = row - rbase;
      if (lr >= 0 && lr < 28) {
        #pragma unroll
        for (int n = 0; n < 4; ++n) {
          f32x4 val = acc[m][n] + bias[n];
          int h0 = wid * 64 + n * 16 + ((lane >> 4) << 2);
          int L = lr * 2048 + h0 * 4;
          *(f32x4*)(sb + (L ^ ((lr & 7) << 4))) = val;
        }
      }
    }
    __syncthreads();
    // tanh + segmented sum: 4 batches x 1344 4-chunks = 5376 tasks
    for (u32 i = tid; i < 5376; i += 512) {
      u32 bb = i / 1344;                             // local batch 0..3 (magic mul)
      u32 rem = i - bb * 1344;
      u32 k4 = rem << 2;                             // 0..5372
      u32 p = k4 >> 8, h0 = k4 & 255;
      int pi = (int)((PIPK >> (3 * p)) & 7);
      int pj = (int)((PJPK >> (3 * p)) & 7);
      int li = (int)bb * 7 + pi, lj = (int)bb * 7 + pj;
      int Lu = (li * 2048 + (int)h0 * 4) ^ ((li & 7) << 4);
      int Lv = (lj * 2048 + 1024 + (int)h0 * 4) ^ ((lj & 7) << 4);
      f32x4 uu = *(const f32x4*)(sb + Lu);
      f32x4 vv = *(const f32x4*)(sb + Lv);
      float t0 = fast_tanh(uu[0] + vv[0]);
      float t1 = fast_tanh(uu[1] + vv[1]);
      float t2 = fast_tanh(uu[2] + vv[2]);
      float t3 = fast_tanh(uu[3] + vv[3]);
      u32 r0 = k4 / 21;                              // magic mul
      int s = (int)(r0 * 21 + 21 - k4);              // 1..21 elems belong to r0
      float p0 = t0 + (s > 1 ? t1 : 0.f) + (s > 2 ? t2 : 0.f) + (s > 3 ? t3 : 0.f);
      int gb = rd * 4 + (int)bb;
      atomicAdd(&relbuf[gb * 256 + (int)r0], p0);
      if (s < 4) {
        float p1 = (s <= 1 ? t1 : 0.f) + (s <= 2 ? t2 : 0.f) + (s <= 3 ? t3 : 0.f);
        atomicAdd(&relbuf[gb * 256 + (int)r0 + 1], p1);
      }
    }
    __syncthreads();
  }
  // writeout: 2048 outputs, 4 per thread (8B coalesced bf16 stores)
  {
    int o = tid * 4;
    int gb = o >> 8, r = o & 255;
    f32x4 s4 = *(const f32x4*)(sb + 57344 + o * 4);
    u32x2 w;
    w[0] = (u32)f2bf(s4[0]) | ((u32)f2bf(s4[1]) << 16);
    w[1] = (u32)f2bf(s4[2]) | ((u32)f2bf(s4[3]) << 16);
    *(u32x2*)(X + (size_t)(b_base + gb) * XCOLS + 1792 + r) = w;
  }
}

// ---------------- GEMM-2: out = tanh(X[16384,2048] @ WfcT^T + b_fc) ----------------
// 128x128 tile, BK=64, 256 thr (4 waves 2x2), m97-style loop
__global__ __launch_bounds__(256, 3) void gemm2(const u16* __restrict__ X, const u16* __restrict__ WT,
                                                const float* __restrict__ b_fc, float* __restrict__ out) {
  __shared__ __align__(16) u16 smem[16384];          // A 16KB | B 16KB
  char* sb = (char*)smem;
  const int tid = threadIdx.x;
  const int wid = tid >> 6, lane = tid & 63;
  const int wr = wid >> 1, wc = wid & 1;
  int bid = blockIdx.x;
  int sw = (bid & 7) * 128 + (bid >> 3);             // XCD-contiguous remap (1024%8==0)
  int bm = sw >> 3, bn = sw & 7;
  const size_t mBase = (size_t)bm * 128;
  const int nBase = bn * 128;
  f32x4 acc[4][4] = {};
  for (int kt = 0; kt < 32; ++kt) {
    const int kb = kt * 64;
    #pragma unroll
    for (int i = 0; i < 4; ++i) {
      int cb = (wid + i * 4) * 64;
      int L = swz((cb + lane) * 16);
      int row = L >> 7, koff = (L & 127) >> 1;
      gload16(X + (mBase + row) * XCOLS + kb + koff, sb + cb * 16);
      gload16(WT + (size_t)(nBase + row) * XCOLS + kb + koff, sb + 16384 + cb * 16);
    }
    __syncthreads();
    #pragma unroll
    for (int kk = 0; kk < 64; kk += 32) {
      short8 a[4], b[4];
      #pragma unroll
      for (int m = 0; m < 4; ++m) {
        int row = wr * 64 + m * 16 + (lane & 15);
        int L = row * 128 + kk * 2 + ((lane >> 4) << 4);
        a[m] = *(const short8*)(sb + swz(L));
      }
      #pragma unroll
      for (int n = 0; n < 4; ++n) {
        int rn = wc * 64 + n * 16 + (lane & 15);
        int L = rn * 128 + kk * 2 + ((lane >> 4) << 4);
        b[n] = *(const short8*)(sb + 16384 + swz(L));
      }
      #pragma unroll
      for (int m = 0; m < 4; ++m)
        #pragma unroll
        for (int n = 0; n < 4; ++n)
          acc[m][n] = __builtin_amdgcn_mfma_f32_16x16x32_bf16(a[m], b[n], acc[m][n], 0, 0, 0);
    }
    __syncthreads();
  }
  #pragma unroll
  for (int m = 0; m < 4; ++m) {
    int row0 = wr * 64 + m * 16 + ((lane >> 4) << 2);
    #pragma unroll
    for (int n = 0; n < 4; ++n) {
      int col = nBase + wc * 64 + n * 16 + (lane & 15);
      float bias = b_fc[col];
      #pragma unroll
      for (int v = 0; v < 4; ++v)
        out[(mBase + row0 + v) * 1024 + col] = fast_tanh(acc[m][n][v] + bias);
    }
  }
}

extern "C" void kernel_launch(void* const* d_in, const int* in_sizes, int n_in,
                              void* d_out, int out_size, void* d_ws, size_t ws_size,
                              hipStream_t stream) {
  const float* ctx   = (const float*)d_in[0];
  const float* W_rel = (const float*)d_in[1];
  const float* b_rel = (const float*)d_in[2];
  const float* W_fc  = (const float*)d_in[3];
  const float* b_fc  = (const float*)d_in[4];
  float* out = (float*)d_out;
  // ws layout: X bf16 [16384,2048] | WcT bf16 [512,256] | WfcT bf16 [1024,2048]
  u16* X    = (u16*)d_ws;
  u16* WcT  = X + (size_t)BATCH * XCOLS;
  u16* WfcT = WcT + 512 * 256;
  prep_ctx<<<2048, 256, 0, stream>>>(ctx, X);
  prep_wrel<<<512, 256, 0, stream>>>(W_rel, WcT);
  prep_wfc<<<dim3(32, 16), 256, 0, stream>>>(W_fc, WfcT);
  gemm1_fused<<<2048, 512, 0, stream>>>(X, WcT, b_rel);
  gemm2<<<1024, 256, 0, stream>>>(X, WfcT, b_fc, out);
}

// Round 4
// 201.704 us; speedup vs baseline: 1.5840x; 1.5840x over previous
//
#include <hip/hip_runtime.h>

typedef unsigned short u16;
typedef unsigned int u32;
typedef __attribute__((ext_vector_type(8))) short short8;   // 8 bf16 = 4 VGPR (MFMA A/B frag)
typedef __attribute__((ext_vector_type(4))) float f32x4;    // MFMA C/D frag
typedef __attribute__((ext_vector_type(2))) u32 u32x2;
typedef const __attribute__((address_space(1))) unsigned int g_u32;
typedef __attribute__((address_space(3))) unsigned int l_u32;

#define BATCH 16384
#define XCOLS 2048

__device__ __forceinline__ void gload16(const void* g, void* l) {
  // async global->LDS, 16B/lane; LDS dest = wave-uniform base + lane*16
  __builtin_amdgcn_global_load_lds((g_u32*)g, (l_u32*)l, 16, 0, 0);
}
__device__ __forceinline__ u16 f2bf(float f) {   // RNE f32->bf16
  u32 x = __builtin_bit_cast(u32, f);
  x += 0x7fffu + ((x >> 16) & 1u);
  return (u16)(x >> 16);
}
// XOR-swizzle on byte offsets with 128B lines: 16B-slot ^= line&7
__device__ __forceinline__ int swz(int P) { return P ^ (((P >> 7) & 7) << 4); }

__device__ __forceinline__ float fast_tanh(float x) {
  // tanh(x) = 1 - 2/(exp2(x*2log2e)+1); saturates correctly at +-inf
  float e = __builtin_amdgcn_exp2f(x * 2.885390081777927f);
  return __builtin_fmaf(-2.0f, __builtin_amdgcn_rcpf(e + 1.0f), 1.0f);
}

// PI/PJ pair tables packed 3 bits per entry (octal digits, p=20..0 left->right)
#define PIPK 0544333222211111000000ULL
#define PJPK 0665654654365432654321ULL

// ---------------- prep: ctx f32 -> bf16 into X[:,0:1792] ----------------
__global__ void prep_ctx(const float* __restrict__ ctx, u16* __restrict__ X) {
  const int total = BATCH * 224;                     // 1792/8 octets per row
  for (int u = blockIdx.x * blockDim.x + threadIdx.x; u < total;
       u += gridDim.x * blockDim.x) {
    int b = u / 224, c8 = u - b * 224;
    const float4* s = (const float4*)(ctx + (size_t)b * 1792 + c8 * 8);
    float4 v0 = s[0], v1 = s[1];
    short8 o;
    o[0] = (short)f2bf(v0.x); o[1] = (short)f2bf(v0.y);
    o[2] = (short)f2bf(v0.z); o[3] = (short)f2bf(v0.w);
    o[4] = (short)f2bf(v1.x); o[5] = (short)f2bf(v1.y);
    o[6] = (short)f2bf(v1.z); o[7] = (short)f2bf(v1.w);
    *(short8*)(X + (size_t)b * XCOLS + c8 * 8) = o;
  }
}

// --------- prep: WcT[n][k] (n<256: W_rel[k][n]; else W_rel[256+k][n-256]) ---------
__global__ void prep_wrel(const float* __restrict__ Wr, u16* __restrict__ WcT) {
  int idx = blockIdx.x * 256 + threadIdx.x;          // 512*256
  if (idx >= 512 * 256) return;
  int n = idx >> 8, k = idx & 255;
  float v = (n < 256) ? Wr[k * 256 + n] : Wr[(256 + k) * 256 + (n - 256)];
  WcT[idx] = f2bf(v);
}

// --------- prep: WfcT[n][k] = bf16(W_fc[k][n]), LDS-tiled transpose ---------
__global__ void prep_wfc(const float* __restrict__ W, u16* __restrict__ WT) {
  __shared__ float t[64][65];
  int k0 = blockIdx.x * 64;                          // 32 blocks (K=2048)
  int n0 = blockIdx.y * 64;                          // 16 blocks (N=1024)
  int tx = threadIdx.x & 63, ty = threadIdx.x >> 6;  // 256 thr
  #pragma unroll
  for (int i = 0; i < 64; i += 4)
    t[ty + i][tx] = W[(size_t)(k0 + ty + i) * 1024 + n0 + tx];
  __syncthreads();
  #pragma unroll
  for (int i = 0; i < 64; i += 4) {
    int n = ty + i;
    WT[(size_t)(n0 + n) * XCOLS + k0 + tx] = f2bf(t[tx][n]);
  }
}

// ---------------- fused GEMM-1 + tanh + shuffled pair-sum ----------------
// block: 8 batches (56 rows pad 64), N=512, K=256, BK=64, 512 thr (8 waves 1x8)
// MFMA operands swapped -> D transposed: h on reg axis (b128 f32 UV staging).
// Epilogue: 4 rounds x 14 rows (2 batches); tanh chunks -> T f32 -> 21-consecutive sums.
__global__ __launch_bounds__(512, 4) void gemm1_fused(u16* __restrict__ X, const u16* __restrict__ WcT,
                                                      const float* __restrict__ b_rel) {
  // 73728 B: GEMM A[0,8192) B[8192,73728)
  // epilogue: UV f32 [0,28672) rows 2048B XOR-swizzled | T f32 [28672,71680)
  __shared__ __align__(16) u16 smem[36864];
  char* sb = (char*)smem;
  const int tid = threadIdx.x;
  const int wid = tid >> 6, lane = tid & 63;
  const int b_base = blockIdx.x * 8;
  // bias frags: waves 0-3 hold U cols (h<256) -> add b_rel there; waves 4-7 add 0
  f32x4 bias[4] = {};
  if (wid < 4) {
    #pragma unroll
    for (int n = 0; n < 4; ++n)
      bias[n] = *(const f32x4*)(b_rel + wid * 64 + n * 16 + ((lane >> 4) << 2));
  }
  f32x4 acc[4][4] = {};
  for (int kt = 0; kt < 4; ++kt) {
    const int kb = kt * 64;
    { // A: 64x64 bf16 = 8KB (rows 128B), 1 gload16/thread
      int L = swz(tid * 16);
      int row = L >> 7, koff = (L & 127) >> 1;
      int r = row < 56 ? row : 55;                   // pad rows clamp
      int bl = r / 7, e = r - bl * 7;
      gload16(X + (size_t)(b_base + bl) * XCOLS + e * 256 + kb + koff, sb + wid * 1024);
    }
    #pragma unroll
    for (int i = 0; i < 8; ++i) {                    // B: 512x64 bf16 = 64KB
      int slot = i * 512 + tid;
      int L = swz(slot * 16);
      int rn = L >> 7, koff = (L & 127) >> 1;
      gload16(WcT + rn * 256 + kb + koff, sb + 8192 + (i * 512 + wid * 64) * 16);
    }
    __syncthreads();
    #pragma unroll
    for (int kk = 0; kk < 64; kk += 32) {
      short8 a[4], b[4];
      #pragma unroll
      for (int m = 0; m < 4; ++m) {
        int row = m * 16 + (lane & 15);
        int L = row * 128 + kk * 2 + ((lane >> 4) << 4);
        a[m] = *(const short8*)(sb + swz(L));
      }
      #pragma unroll
      for (int n = 0; n < 4; ++n) {
        int rn = wid * 64 + n * 16 + (lane & 15);
        int L = rn * 128 + kk * 2 + ((lane >> 4) << 4);
        b[n] = *(const short8*)(sb + 8192 + swz(L));
      }
      // swapped operands: D[h][batchrow] -> h on reg axis, batch row on lane&15
      #pragma unroll
      for (int m = 0; m < 4; ++m)
        #pragma unroll
        for (int n = 0; n < 4; ++n)
          acc[m][n] = __builtin_amdgcn_mfma_f32_16x16x32_bf16(b[n], a[m], acc[m][n], 0, 0, 0);
    }
    __syncthreads();
  }
  // ---- epilogue ----
  float* Tbuf = (float*)(sb + 28672);
  auto stage = [&](int rd) {
    #pragma unroll
    for (int m = 0; m < 4; ++m) {
      int row = m * 16 + (lane & 15);
      int lr = row - rd * 14;
      if (lr >= 0 && lr < 14) {
        #pragma unroll
        for (int n = 0; n < 4; ++n) {
          f32x4 val = acc[m][n] + bias[n];
          int h0 = wid * 64 + n * 16 + ((lane >> 4) << 2);
          int L = lr * 2048 + h0 * 4;
          *(f32x4*)(sb + (L ^ ((lr & 7) << 4))) = val;
        }
      }
    }
  };
  stage(0);
  __syncthreads();
  for (int rd = 0; rd < 4; ++rd) {
    // tanh pass: 2 batches x 1344 4-chunks; dense f32x4 reads, dense T writes
    for (int i = tid; i < 2688; i += 512) {
      int bb = i >= 1344;
      int k4 = (i - bb * 1344) << 2;                 // 0..5372
      int p = k4 >> 8, h0 = k4 & 255;
      int li = bb * 7 + (int)((PIPK >> (3 * p)) & 7);
      int lj = bb * 7 + (int)((PJPK >> (3 * p)) & 7);
      int Lu = (li * 2048 + h0 * 4) ^ ((li & 7) << 4);
      int Lv = (lj * 2048 + 1024 + h0 * 4) ^ ((lj & 7) << 4);
      f32x4 uu = *(const f32x4*)(sb + Lu);
      f32x4 vv = *(const f32x4*)(sb + Lv);
      f32x4 t;
      t[0] = fast_tanh(uu[0] + vv[0]);
      t[1] = fast_tanh(uu[1] + vv[1]);
      t[2] = fast_tanh(uu[2] + vv[2]);
      t[3] = fast_tanh(uu[3] + vv[3]);
      *(f32x4*)(sb + 28672 + (bb * 5376 + k4) * 4) = t;
    }
    __syncthreads();
    { // sum pass: 512 outputs (2 batches x 256), 21 consecutive f32 each
      int bb = tid >> 8, r = tid & 255;
      const float* T = Tbuf + bb * 5376 + r * 21;
      float s = 0.f;
      #pragma unroll
      for (int c = 0; c < 21; ++c) s += T[c];
      X[(size_t)(b_base + rd * 2 + bb) * XCOLS + 1792 + r] = f2bf(s);
    }
    if (rd < 3) stage(rd + 1);                       // UV disjoint from T: overlap with sum
    __syncthreads();
  }
}

// ---------------- GEMM-2: out = tanh(X[16384,2048] @ WfcT^T + b_fc) ----------------
// 128x128 tile, BK=64, 256 thr (4 waves 2x2), m97-style loop
__global__ __launch_bounds__(256, 3) void gemm2(const u16* __restrict__ X, const u16* __restrict__ WT,
                                                const float* __restrict__ b_fc, float* __restrict__ out) {
  __shared__ __align__(16) u16 smem[16384];          // A 16KB | B 16KB
  char* sb = (char*)smem;
  const int tid = threadIdx.x;
  const int wid = tid >> 6, lane = tid & 63;
  const int wr = wid >> 1, wc = wid & 1;
  int bid = blockIdx.x;
  int sw = (bid & 7) * 128 + (bid >> 3);             // XCD-contiguous remap (1024%8==0)
  int bm = sw >> 3, bn = sw & 7;
  const size_t mBase = (size_t)bm * 128;
  const int nBase = bn * 128;
  f32x4 acc[4][4] = {};
  for (int kt = 0; kt < 32; ++kt) {
    const int kb = kt * 64;
    #pragma unroll
    for (int i = 0; i < 4; ++i) {
      int cb = (wid + i * 4) * 64;
      int L = swz((cb + lane) * 16);
      int row = L >> 7, koff = (L & 127) >> 1;
      gload16(X + (mBase + row) * XCOLS + kb + koff, sb + cb * 16);
      gload16(WT + (size_t)(nBase + row) * XCOLS + kb + koff, sb + 16384 + cb * 16);
    }
    __syncthreads();
    #pragma unroll
    for (int kk = 0; kk < 64; kk += 32) {
      short8 a[4], b[4];
      #pragma unroll
      for (int m = 0; m < 4; ++m) {
        int row = wr * 64 + m * 16 + (lane & 15);
        int L = row * 128 + kk * 2 + ((lane >> 4) << 4);
        a[m] = *(const short8*)(sb + swz(L));
      }
      #pragma unroll
      for (int n = 0; n < 4; ++n) {
        int rn = wc * 64 + n * 16 + (lane & 15);
        int L = rn * 128 + kk * 2 + ((lane >> 4) << 4);
        b[n] = *(const short8*)(sb + 16384 + swz(L));
      }
      #pragma unroll
      for (int m = 0; m < 4; ++m)
        #pragma unroll
        for (int n = 0; n < 4; ++n)
          acc[m][n] = __builtin_amdgcn_mfma_f32_16x16x32_bf16(a[m], b[n], acc[m][n], 0, 0, 0);
    }
    __syncthreads();
  }
  #pragma unroll
  for (int m = 0; m < 4; ++m) {
    int row0 = wr * 64 + m * 16 + ((lane >> 4) << 2);
    #pragma unroll
    for (int n = 0; n < 4; ++n) {
      int col = nBase + wc * 64 + n * 16 + (lane & 15);
      float bias = b_fc[col];
      #pragma unroll
      for (int v = 0; v < 4; ++v)
        out[(mBase + row0 + v) * 1024 + col] = fast_tanh(acc[m][n][v] + bias);
    }
  }
}

extern "C" void kernel_launch(void* const* d_in, const int* in_sizes, int n_in,
                              void* d_out, int out_size, void* d_ws, size_t ws_size,
                              hipStream_t stream) {
  const float* ctx   = (const float*)d_in[0];
  const float* W_rel = (const float*)d_in[1];
  const float* b_rel = (const float*)d_in[2];
  const float* W_fc  = (const float*)d_in[3];
  const float* b_fc  = (const float*)d_in[4];
  float* out = (float*)d_out;
  // ws layout: X bf16 [16384,2048] | WcT bf16 [512,256] | WfcT bf16 [1024,2048]
  u16* X    = (u16*)d_ws;
  u16* WcT  = X + (size_t)BATCH * XCOLS;
  u16* WfcT = WcT + 512 * 256;
  prep_ctx<<<2048, 256, 0, stream>>>(ctx, X);
  prep_wrel<<<512, 256, 0, stream>>>(W_rel, WcT);
  prep_wfc<<<dim3(32, 16), 256, 0, stream>>>(W_fc, WfcT);
  gemm1_fused<<<2048, 512, 0, stream>>>(X, WcT, b_rel);
  gemm2<<<1024, 256, 0, stream>>>(X, WfcT, b_fc, out);
}